// Round 8
// baseline (73.576 us; speedup 1.0000x reference)
//
#include <hip/hip_runtime.h>

constexpr int B = 4, C = 32, H = 512, W = 512, Q = 65536;
constexpr int CP = 4;            // channels per thread / per ws pixel
constexpr int NCHUNK = C / CP;   // 8 channel-chunks
constexpr int NXCD = 8;
constexpr size_t PLANE = (size_t)H * W;                         // 262144
constexpr size_t WS_NEED = (size_t)B * NCHUNK * PLANE * 8 + 16; // 64 MB + pad

typedef float vfloat4 __attribute__((ext_vector_type(4)));     // clang-native

__device__ __forceinline__ unsigned short f2bf(float f) {
    unsigned u = __float_as_uint(f);
    u += 0x7fffu + ((u >> 16) & 1u);   // round-to-nearest-even
    return (unsigned short)(u >> 16);
}
__device__ __forceinline__ float bf2f(unsigned short s) {
    return __uint_as_float((unsigned)s << 16);
}

// 16B row fragment: channels of pixel j0 then channels of j0+1 (8B-aligned).
struct __attribute__((packed, aligned(8))) row8 { unsigned short u[8]; };

// ---- K1: [B,C,H,W] f32 -> [pair, PLANE, 4ch] bf16 ----
// XCD-aligned with K2's consumer mapping: pair = xcd + 8*pair_local, so each
// pair's ws lines are written through the L2 of the XCD that will gather them.
// Input reads are nontemporal so the 128 MB f32 stream doesn't evict the
// freshly-written ws lines. Each thread: 4 pixels x 4 channels.
__global__ __launch_bounds__(256) void interleave_kernel(
    const float* __restrict__ input, ushort4* __restrict__ ws)
{
    int bid = blockIdx.x;              // 8192 blocks
    int xcd  = bid & (NXCD - 1);
    int slot = bid >> 3;               // 0..1023
    int pair = xcd + NXCD * (slot >> 8);   // 0..31, matches K2 mapping
    int slice = slot & 255;            // 256 slices per pair
    int b = pair & 3, chunk = pair >> 2;

    int px0 = (slice << 10) | ((int)threadIdx.x << 2);   // 4 pixels/thread
    const float* p = input + ((size_t)b * C + chunk * CP) * PLANE + px0;

    vfloat4 f0 = __builtin_nontemporal_load(reinterpret_cast<const vfloat4*>(p));
    vfloat4 f1 = __builtin_nontemporal_load(reinterpret_cast<const vfloat4*>(p + PLANE));
    vfloat4 f2 = __builtin_nontemporal_load(reinterpret_cast<const vfloat4*>(p + 2 * PLANE));
    vfloat4 f3 = __builtin_nontemporal_load(reinterpret_cast<const vfloat4*>(p + 3 * PLANE));

    ushort4* wp = ws + (size_t)pair * PLANE + px0;
    wp[0] = { f2bf(f0.x), f2bf(f1.x), f2bf(f2.x), f2bf(f3.x) };
    wp[1] = { f2bf(f0.y), f2bf(f1.y), f2bf(f2.y), f2bf(f3.y) };
    wp[2] = { f2bf(f0.z), f2bf(f1.z), f2bf(f2.z), f2bf(f3.z) };
    wp[3] = { f2bf(f0.w), f2bf(f1.w), f2bf(f2.w), f2bf(f3.w) };
}

// ---- K2: gather from interleaved bf16 (2 scattered 16B loads / thread) ----
// bid = (slot<<3)|xcd pins each (chunk,b) pair to one XCD; pairs consumed in
// REVERSE pair_local order so the first pair gathered is the last K1 wrote
// on this XCD (its 2 MB is still L2-resident).
__global__ __launch_bounds__(256) void dgs_gather(
    const ushort4* __restrict__ ws,    // [32, PLANE] x 4ch bf16
    const float* __restrict__ grid,    // [B,Q,3]
    const float* __restrict__ fsw,     // [B]
    const float* __restrict__ fsh,     // [B]
    float* __restrict__ out)           // [B,C,4,Q]
{
    int bid = blockIdx.x;
    int xcd  = bid & (NXCD - 1);
    int slot = bid >> 3;               // 0..1023
    int pair = xcd + NXCD * (3 - (slot >> 8));   // reverse consumption order
    int qblk = slot & 255;
    int chunk = pair >> 2;             // 0..7
    int b     = pair & 3;              // 0..3
    int q = (qblk << 8) | (int)threadIdx.x;

    const float* g3 = grid + (size_t)(b * Q + q) * 3;
    float gx = g3[0];
    float gy = g3[1];
    float gz = g3[2];

    const float sx = 0.5f * (float)(W - 1);
    const float sy = 0.5f * (float)(H - 1);
    float jx = (gx + 1.0f) * sx;
    float iy = (gy + 1.0f) * sy;
    float j0f = floorf(jx);
    float i0f = floorf(iy);
    float tx = jx - j0f;
    float ty = iy - i0f;
    int j0 = (int)j0f;
    int i0 = (int)i0f;
    int j1 = j0 + 1, i1 = i0 + 1;

    float m00 = (i0 >= 0 && i0 < H && j0 >= 0 && j0 < W) ? 1.f : 0.f;
    float m01 = (i0 >= 0 && i0 < H && j1 >= 0 && j1 < W) ? 1.f : 0.f;
    float m10 = (i1 >= 0 && i1 < H && j0 >= 0 && j0 < W) ? 1.f : 0.f;
    float m11 = (i1 >= 0 && i1 < H && j1 >= 0 && j1 < W) ? 1.f : 0.f;
    int i0c = min(max(i0, 0), H - 1), i1c = min(max(i1, 0), H - 1);
    int j0c = min(max(j0, 0), W - 1);

    const ushort4* wp = ws + (size_t)pair * PLANE;
    row8 v0 = *reinterpret_cast<const row8*>(wp + i0c * W + j0c);
    row8 v1 = *reinterpret_cast<const row8*>(wp + i1c * W + j0c);

    float fw = fsw[b];
    float fh = fsh[b];
    float inv_z = 1.0f / gz;
    float fw_over_z = fw * inv_z;
    float fh_over_z = fh * inv_z;
    float x_over_z = gx * inv_z;
    float y_over_z = gy * inv_z;

    float omtx = 1.0f - tx, omty = 1.0f - ty;

    const int cg0 = chunk * CP;
    float* ob = out + ((size_t)(b * C + cg0) * 4) * Q + q;

    #pragma unroll
    for (int c = 0; c < CP; ++c) {
        float g00 = bf2f(v0.u[c])     * m00;
        float g01 = bf2f(v0.u[c + 4]) * m01;
        float g10 = bf2f(v1.u[c])     * m10;
        float g11 = bf2f(v1.u[c + 4]) * m11;

        float top = g00 * omtx + g01 * tx;
        float bot = g10 * omtx + g11 * tx;
        float phi = top * omty + bot * ty;
        float dphi_djx = (g01 - g00) * omty + (g11 - g10) * ty;
        float dphi_diy = (g10 - g00) * omtx + (g11 - g01) * tx;
        float phi_on_j = dphi_djx * sx;
        float phi_on_i = dphi_diy * sy;

        float* o = ob + (size_t)c * 4 * Q;
        __builtin_nontemporal_store(phi, o);
        __builtin_nontemporal_store(phi_on_j * fw_over_z, o + (size_t)Q);
        __builtin_nontemporal_store(phi_on_i * fh_over_z, o + (size_t)2 * Q);
        __builtin_nontemporal_store(-phi_on_i * y_over_z - phi_on_j * x_over_z,
                                    o + (size_t)3 * Q);
    }
}

// ---- fallback: round-4 proven kernel (direct f32 gather) ----
struct __attribute__((packed, aligned(4))) f2pair { float x, y; };

__global__ __launch_bounds__(256) void dgs_kernel(
    const float* __restrict__ input, const float* __restrict__ grid,
    const float* __restrict__ fsw, const float* __restrict__ fsh,
    float* __restrict__ out)
{
    int bid = blockIdx.x;
    int xcd  = bid & (NXCD - 1);
    int slot = bid >> 3;
    int pair = xcd + NXCD * (slot >> 8);
    int qblk = slot & 255;
    int chunk = pair >> 2;
    int b     = pair & 3;
    int q = (qblk << 8) | (int)threadIdx.x;

    const float* g3 = grid + (size_t)(b * Q + q) * 3;
    float gx = g3[0], gy = g3[1], gz = g3[2];
    const float sx = 0.5f * (float)(W - 1);
    const float sy = 0.5f * (float)(H - 1);
    float jx = (gx + 1.0f) * sx;
    float iy = (gy + 1.0f) * sy;
    float j0f = floorf(jx), i0f = floorf(iy);
    float tx = jx - j0f, ty = iy - i0f;
    int j0 = (int)j0f, i0 = (int)i0f;
    int j1 = j0 + 1, i1 = i0 + 1;
    float m00 = (i0 >= 0 && i0 < H && j0 >= 0 && j0 < W) ? 1.f : 0.f;
    float m01 = (i0 >= 0 && i0 < H && j1 >= 0 && j1 < W) ? 1.f : 0.f;
    float m10 = (i1 >= 0 && i1 < H && j0 >= 0 && j0 < W) ? 1.f : 0.f;
    float m11 = (i1 >= 0 && i1 < H && j1 >= 0 && j1 < W) ? 1.f : 0.f;
    int i0c = min(max(i0, 0), H - 1), i1c = min(max(i1, 0), H - 1);
    int j0c = min(max(j0, 0), W - 1);
    int off00 = i0c * W + j0c;
    int off10 = i1c * W + j0c;
    float fw = fsw[b], fh = fsh[b];
    float inv_z = 1.0f / gz;
    float fw_over_z = fw * inv_z, fh_over_z = fh * inv_z;
    float x_over_z = gx * inv_z, y_over_z = gy * inv_z;
    float omtx = 1.0f - tx, omty = 1.0f - ty;
    const int cg0 = chunk * CP;
    const float* inb = input + ((size_t)b * C + cg0) * PLANE;
    float* ob = out + ((size_t)(b * C + cg0) * 4) * Q + q;
    #pragma unroll
    for (int c = 0; c < CP; ++c) {
        const float* p = inb + (size_t)c * PLANE;
        f2pair v0 = *reinterpret_cast<const f2pair*>(p + off00);
        f2pair v1 = *reinterpret_cast<const f2pair*>(p + off10);
        float g00 = v0.x * m00, g01 = v0.y * m01;
        float g10 = v1.x * m10, g11 = v1.y * m11;
        float top = g00 * omtx + g01 * tx;
        float bot = g10 * omtx + g11 * tx;
        float phi = top * omty + bot * ty;
        float dphi_djx = (g01 - g00) * omty + (g11 - g10) * ty;
        float dphi_diy = (g10 - g00) * omtx + (g11 - g01) * tx;
        float phi_on_j = dphi_djx * sx;
        float phi_on_i = dphi_diy * sy;
        float* o = ob + (size_t)c * 4 * Q;
        o[0]             = phi;
        o[(size_t)Q]     = phi_on_j * fw_over_z;
        o[(size_t)2 * Q] = phi_on_i * fh_over_z;
        o[(size_t)3 * Q] = -phi_on_i * y_over_z - phi_on_j * x_over_z;
    }
}

extern "C" void kernel_launch(void* const* d_in, const int* in_sizes, int n_in,
                              void* d_out, int out_size, void* d_ws, size_t ws_size,
                              hipStream_t stream) {
    const float* input = (const float*)d_in[0];
    const float* grid  = (const float*)d_in[1];
    const float* fsw   = (const float*)d_in[2];
    const float* fsh   = (const float*)d_in[3];
    float* out = (float*)d_out;

    if (ws_size >= WS_NEED) {
        ushort4* ws = (ushort4*)d_ws;
        // K1: 2M threads (4 px each) = 8192 blocks, XCD-aligned with K2
        hipLaunchKernelGGL(interleave_kernel, dim3(8192), dim3(256), 0,
                           stream, input, ws);
        int t2 = B * Q * NCHUNK;                    // one thread per (chunk,b,q)
        hipLaunchKernelGGL(dgs_gather, dim3(t2 / 256), dim3(256), 0, stream,
                           ws, grid, fsw, fsh, out);
    } else {
        int total = B * Q * NCHUNK;
        hipLaunchKernelGGL(dgs_kernel, dim3(total / 256), dim3(256), 0, stream,
                           input, grid, fsw, fsh, out);
    }
}

// Round 9
// 69.244 us; speedup vs baseline: 1.0626x; 1.0626x over previous
//
#include <hip/hip_runtime.h>

constexpr int B = 4, C = 32, H = 512, W = 512, Q = 65536;
constexpr int CP = 4;            // channels per thread / per ws pixel
constexpr int NCHUNK = C / CP;   // 8 channel-chunks
constexpr int NXCD = 8;
constexpr size_t PLANE = (size_t)H * W;                         // 262144
constexpr size_t WS_NEED = (size_t)B * NCHUNK * PLANE * 8 + 16; // 64 MB + pad

__device__ __forceinline__ unsigned short f2bf(float f) {
    unsigned u = __float_as_uint(f);
    u += 0x7fffu + ((u >> 16) & 1u);   // round-to-nearest-even
    return (unsigned short)(u >> 16);
}
__device__ __forceinline__ float bf2f(unsigned short s) {
    return __uint_as_float((unsigned)s << 16);
}

// 16B row fragment: channels of pixel j0 then channels of j0+1 (8B-aligned).
struct __attribute__((packed, aligned(8))) row8 { unsigned short u[8]; };

// ---- K1: [B,C,H,W] f32  ->  [B*NCHUNK, H*W, 4ch] bf16 (fully coalesced) ----
__global__ __launch_bounds__(256) void interleave_kernel(
    const float* __restrict__ input, ushort4* __restrict__ ws)
{
    int t = blockIdx.x * 256 + (int)threadIdx.x;  // one thread per ws pixel
    int px = t & (int)(PLANE - 1);
    int pr = t >> 18;                             // b*NCHUNK + chunk
    int b = pr >> 3, chunk = pr & 7;
    const float* p = input + ((size_t)b * C + chunk * CP) * PLANE + px;
    ushort4 v;
    v.x = f2bf(p[0]);
    v.y = f2bf(p[PLANE]);
    v.z = f2bf(p[2 * PLANE]);
    v.w = f2bf(p[3 * PLANE]);
    ws[(size_t)pr * PLANE + px] = v;
}

// ---- K2: gather from interleaved bf16 (2 scattered 16B loads / thread) ----
// Block scheduling: bid = (slot<<3)|xcd pins each (chunk,b) pair to one XCD;
// per-pair working set is 2 MB bf16 (half an XCD L2).
__global__ __launch_bounds__(256) void dgs_gather(
    const ushort4* __restrict__ ws,    // [B*NCHUNK, PLANE] x 4ch bf16
    const float* __restrict__ grid,    // [B,Q,3]
    const float* __restrict__ fsw,     // [B]
    const float* __restrict__ fsh,     // [B]
    float* __restrict__ out)           // [B,C,4,Q]
{
    int bid = blockIdx.x;
    int xcd  = bid & (NXCD - 1);
    int slot = bid >> 3;               // 0..1023
    int pair = xcd + NXCD * (slot >> 8);   // 0..31  == (chunk,b) id
    int qblk = slot & 255;
    int chunk = pair >> 2;             // 0..7
    int b     = pair & 3;              // 0..3
    int q = (qblk << 8) | (int)threadIdx.x;

    const float* g3 = grid + (size_t)(b * Q + q) * 3;
    float gx = g3[0];
    float gy = g3[1];
    float gz = g3[2];

    const float sx = 0.5f * (float)(W - 1);
    const float sy = 0.5f * (float)(H - 1);
    float jx = (gx + 1.0f) * sx;
    float iy = (gy + 1.0f) * sy;
    float j0f = floorf(jx);
    float i0f = floorf(iy);
    float tx = jx - j0f;
    float ty = iy - i0f;
    int j0 = (int)j0f;
    int i0 = (int)i0f;
    int j1 = j0 + 1, i1 = i0 + 1;

    float m00 = (i0 >= 0 && i0 < H && j0 >= 0 && j0 < W) ? 1.f : 0.f;
    float m01 = (i0 >= 0 && i0 < H && j1 >= 0 && j1 < W) ? 1.f : 0.f;
    float m10 = (i1 >= 0 && i1 < H && j0 >= 0 && j0 < W) ? 1.f : 0.f;
    float m11 = (i1 >= 0 && i1 < H && j1 >= 0 && j1 < W) ? 1.f : 0.f;
    int i0c = min(max(i0, 0), H - 1), i1c = min(max(i1, 0), H - 1);
    int j0c = min(max(j0, 0), W - 1);

    const ushort4* wp = ws + (size_t)(b * NCHUNK + chunk) * PLANE;
    row8 v0 = *reinterpret_cast<const row8*>(wp + i0c * W + j0c);
    row8 v1 = *reinterpret_cast<const row8*>(wp + i1c * W + j0c);

    float fw = fsw[b];
    float fh = fsh[b];
    float inv_z = 1.0f / gz;
    float fw_over_z = fw * inv_z;
    float fh_over_z = fh * inv_z;
    float x_over_z = gx * inv_z;
    float y_over_z = gy * inv_z;

    float omtx = 1.0f - tx, omty = 1.0f - ty;

    const int cg0 = chunk * CP;
    float* ob = out + ((size_t)(b * C + cg0) * 4) * Q + q;

    #pragma unroll
    for (int c = 0; c < CP; ++c) {
        float g00 = bf2f(v0.u[c])     * m00;
        float g01 = bf2f(v0.u[c + 4]) * m01;
        float g10 = bf2f(v1.u[c])     * m10;
        float g11 = bf2f(v1.u[c + 4]) * m11;

        float top = g00 * omtx + g01 * tx;
        float bot = g10 * omtx + g11 * tx;
        float phi = top * omty + bot * ty;
        float dphi_djx = (g01 - g00) * omty + (g11 - g10) * ty;
        float dphi_diy = (g10 - g00) * omtx + (g11 - g01) * tx;
        float phi_on_j = dphi_djx * sx;
        float phi_on_i = dphi_diy * sy;

        float* o = ob + (size_t)c * 4 * Q;
        __builtin_nontemporal_store(phi, o);
        __builtin_nontemporal_store(phi_on_j * fw_over_z, o + (size_t)Q);
        __builtin_nontemporal_store(phi_on_i * fh_over_z, o + (size_t)2 * Q);
        __builtin_nontemporal_store(-phi_on_i * y_over_z - phi_on_j * x_over_z,
                                    o + (size_t)3 * Q);
    }
}

// ---- fallback: round-4 proven kernel (direct f32 gather) ----
struct __attribute__((packed, aligned(4))) f2pair { float x, y; };

__global__ __launch_bounds__(256) void dgs_kernel(
    const float* __restrict__ input, const float* __restrict__ grid,
    const float* __restrict__ fsw, const float* __restrict__ fsh,
    float* __restrict__ out)
{
    int bid = blockIdx.x;
    int xcd  = bid & (NXCD - 1);
    int slot = bid >> 3;
    int pair = xcd + NXCD * (slot >> 8);
    int qblk = slot & 255;
    int chunk = pair >> 2;
    int b     = pair & 3;
    int q = (qblk << 8) | (int)threadIdx.x;

    const float* g3 = grid + (size_t)(b * Q + q) * 3;
    float gx = g3[0], gy = g3[1], gz = g3[2];
    const float sx = 0.5f * (float)(W - 1);
    const float sy = 0.5f * (float)(H - 1);
    float jx = (gx + 1.0f) * sx;
    float iy = (gy + 1.0f) * sy;
    float j0f = floorf(jx), i0f = floorf(iy);
    float tx = jx - j0f, ty = iy - i0f;
    int j0 = (int)j0f, i0 = (int)i0f;
    int j1 = j0 + 1, i1 = i0 + 1;
    float m00 = (i0 >= 0 && i0 < H && j0 >= 0 && j0 < W) ? 1.f : 0.f;
    float m01 = (i0 >= 0 && i0 < H && j1 >= 0 && j1 < W) ? 1.f : 0.f;
    float m10 = (i1 >= 0 && i1 < H && j0 >= 0 && j0 < W) ? 1.f : 0.f;
    float m11 = (i1 >= 0 && i1 < H && j1 >= 0 && j1 < W) ? 1.f : 0.f;
    int i0c = min(max(i0, 0), H - 1), i1c = min(max(i1, 0), H - 1);
    int j0c = min(max(j0, 0), W - 1);
    int off00 = i0c * W + j0c;
    int off10 = i1c * W + j0c;
    float fw = fsw[b], fh = fsh[b];
    float inv_z = 1.0f / gz;
    float fw_over_z = fw * inv_z, fh_over_z = fh * inv_z;
    float x_over_z = gx * inv_z, y_over_z = gy * inv_z;
    float omtx = 1.0f - tx, omty = 1.0f - ty;
    const int cg0 = chunk * CP;
    const float* inb = input + ((size_t)b * C + cg0) * PLANE;
    float* ob = out + ((size_t)(b * C + cg0) * 4) * Q + q;
    #pragma unroll
    for (int c = 0; c < CP; ++c) {
        const float* p = inb + (size_t)c * PLANE;
        f2pair v0 = *reinterpret_cast<const f2pair*>(p + off00);
        f2pair v1 = *reinterpret_cast<const f2pair*>(p + off10);
        float g00 = v0.x * m00, g01 = v0.y * m01;
        float g10 = v1.x * m10, g11 = v1.y * m11;
        float top = g00 * omtx + g01 * tx;
        float bot = g10 * omtx + g11 * tx;
        float phi = top * omty + bot * ty;
        float dphi_djx = (g01 - g00) * omty + (g11 - g10) * ty;
        float dphi_diy = (g10 - g00) * omtx + (g11 - g01) * tx;
        float phi_on_j = dphi_djx * sx;
        float phi_on_i = dphi_diy * sy;
        float* o = ob + (size_t)c * 4 * Q;
        o[0]             = phi;
        o[(size_t)Q]     = phi_on_j * fw_over_z;
        o[(size_t)2 * Q] = phi_on_i * fh_over_z;
        o[(size_t)3 * Q] = -phi_on_i * y_over_z - phi_on_j * x_over_z;
    }
}

extern "C" void kernel_launch(void* const* d_in, const int* in_sizes, int n_in,
                              void* d_out, int out_size, void* d_ws, size_t ws_size,
                              hipStream_t stream) {
    const float* input = (const float*)d_in[0];
    const float* grid  = (const float*)d_in[1];
    const float* fsw   = (const float*)d_in[2];
    const float* fsh   = (const float*)d_in[3];
    float* out = (float*)d_out;

    if (ws_size >= WS_NEED) {
        ushort4* ws = (ushort4*)d_ws;
        int t1 = B * NCHUNK * (int)PLANE;           // 8M ws pixels
        hipLaunchKernelGGL(interleave_kernel, dim3(t1 / 256), dim3(256), 0,
                           stream, input, ws);
        int t2 = B * Q * NCHUNK;                    // one thread per (chunk,b,q)
        hipLaunchKernelGGL(dgs_gather, dim3(t2 / 256), dim3(256), 0, stream,
                           ws, grid, fsw, fsh, out);
    } else {
        int total = B * Q * NCHUNK;
        hipLaunchKernelGGL(dgs_kernel, dim3(total / 256), dim3(256), 0, stream,
                           input, grid, fsw, fsh, out);
    }
}